// Round 3
// baseline (301.797 us; speedup 1.0000x reference)
//
#include <hip/hip_runtime.h>
#include <hip/hip_bf16.h>
#include <cstdint>
#include <cstddef>

// WideLSTM: N=32 blocks, I=64, H=128, B=16, T=256.
// 128 WGs = 32 blocks x 4 batch-groups, 1024 thr = 16 waves = 4 waves/SIMD.
// GATE-INTERLEAVED A-TILES: each 16-row A-tile = 4 h x 4 gates, row r=4*dh+j
// (weight row g = 128*j + h).  With C row = 4*quad + reg, each lane's f32x4
// acc holds ALL FOUR gate pre-activations for one (h,batch): reg = gate.
// -> no cross-wave gate/K exchange, no pbuf, ONE lgkm-only barrier per step.
// Wave wv owns h-range [8wv, 8wv+8) as 2 tiles (T=0: h+quad, T=1: h+4+quad).
// Per wave per step: 8 in-window MFMAs (Whh, two 2-deep chains per tile) +
// 4 tail MFMAs (Wih*x(S+1) -> acpre, hoisted, independent of h).  Epilogue:
// lanes e2<2 handle tile0, e2>=2 tile1 (cndmask select); writers e2 in {0,2}.
// B-frag layout, hbuf/xbuf bank-tuning, x staging identical to prior version.

#define TSTEPS 256

typedef float  f32x4  __attribute__((ext_vector_type(4)));
typedef float  f32x2  __attribute__((ext_vector_type(2)));
typedef __bf16 bf16x8 __attribute__((ext_vector_type(8)));
typedef short  s16x8  __attribute__((ext_vector_type(8)));

union Frag { s16x8 s; bf16x8 b; };

#define KSIG -1.4426950408889634f   // -1/ln2 (sigmoid)
#define KTAN  2.8853900817779268f   //  2/ln2 (tanh)

__device__ __forceinline__ short f2bf(float f) {
  uint32_t u = __builtin_bit_cast(uint32_t, f);
  u += 0x7fffu + ((u >> 16) & 1u);
  return (short)(u >> 16);
}

// lgkm-only barrier: global loads/stores stay in flight across it
__device__ __forceinline__ void sync_lds() {
  asm volatile("s_waitcnt lgkmcnt(0)" ::: "memory");
  __builtin_amdgcn_s_barrier();
  asm volatile("" ::: "memory");
}

__device__ __forceinline__ float sig2(float z) {   // rcp(1 + exp2(z))
  return __builtin_amdgcn_rcpf(1.f + __builtin_amdgcn_exp2f(z));
}

__device__ __forceinline__ f32x4 mf(const Frag a, const Frag bb, f32x4 c) {
  return __builtin_amdgcn_mfma_f32_16x16x32_bf16(a.b, bb.b, c, 0, 0, 0);
}

__global__ __launch_bounds__(1024, 4) void wide_lstm(
    const float* __restrict__ x,   const float* __restrict__ h0,
    const float* __restrict__ c0,  const float* __restrict__ wih,
    const float* __restrict__ whh, const float* __restrict__ bih,
    const float* __restrict__ bhh, float* __restrict__ out)
{
  const int n     = blockIdx.x & 31;
  const int bg    = blockIdx.x >> 5;     // batch group: batches [4bg, 4bg+4)
  const int tid   = threadIdx.x;
  const int wv    = tid >> 6;            // wave 0..15: h-range [8wv, 8wv+8)
  const int lane  = tid & 63;
  const int col   = lane & 15;
  const int quad  = lane >> 4;
  const int b4    = col & 3;             // batch within group
  const int e2    = col >> 2;            // dup index 0..3
  const int tsel  = e2 >> 1;             // tile this lane's epilogue owns
  const int hbase = 8 * wv;
  const int hl    = hbase + quad + 4 * tsel;  // this lane's h (0..127)
  const int b     = 4 * bg + b4;         // global batch this lane updates
  const bool wr   = ((e2 & 1) == 0);     // writer lane (one per (h,b))

  // h: 4 rows x stride 144 shorts (bank-tuned); x: 4 rows x stride 96
  __shared__ alignas(16) short hbuf[2][4 * 144];
  __shared__ alignas(16) short xbuf[2][4 * 96];

  // ---- weights -> persistent A-fragments, gate-interleaved rows ----
  // tile T row r=col: dh = col>>2, j = col&3; g = 128*(col&3) + hbase + 4T + (col>>2)
  // lane holds W[g][k = 32s + quad*8 + jj]
  Frag wfr[6][2];
#pragma unroll
  for (int T = 0; T < 2; ++T) {
    const int g = 128 * (col & 3) + hbase + 4 * T + (col >> 2);
#pragma unroll
    for (int s = 0; s < 6; ++s) {
      const int k0 = 32 * s + quad * 8;
      const float* p = (s < 2) ? (wih + (size_t)(n * 512 + g) * 64  + k0)
                               : (whh + (size_t)(n * 512 + g) * 128 + (k0 - 64));
      const f32x4 lo = *(const f32x4*)p;
      const f32x4 hi = *(const f32x4*)(p + 4);
      Frag f;
      f.s[0]=f2bf(lo[0]); f.s[1]=f2bf(lo[1]); f.s[2]=f2bf(lo[2]); f.s[3]=f2bf(lo[3]);
      f.s[4]=f2bf(hi[0]); f.s[5]=f2bf(hi[1]); f.s[6]=f2bf(hi[2]); f.s[7]=f2bf(hi[3]);
      wfr[s][T] = f;
    }
  }

  // ---- bias in acc layout: cb[T][reg] = bias[g = 128*reg + hbase + 4T + quad] ----
  f32x4 cb[2];
#pragma unroll
  for (int T = 0; T < 2; ++T) {
#pragma unroll
    for (int r = 0; r < 4; ++r) {
      const int g = n * 512 + 128 * r + hbase + 4 * T + quad;
      cb[T][r] = bih[g] + bhh[g];
    }
  }

  // ---- init h(0) ----
  if (tid < 256) {
    const int bi = tid >> 6, j2 = (tid & 63) * 2;
    const f32x2 hv = *(const f32x2*)(h0 + (size_t)(4 * bg + bi) * 4096 + n * 128 + j2);
    *(uint32_t*)&hbuf[0][bi * 144 + j2] =
        (uint32_t)(uint16_t)f2bf(hv[0]) | ((uint32_t)(uint16_t)f2bf(hv[1]) << 16);
  }
  // ---- x staging (waves 0-3): x(1)->xbuf[1]; xr=x(2); cursor x(3) ----
  const int sxoff = ((tid >> 6) & 3) * 96 + (tid & 63);
  float xr = 0.f;
  const float* xnext = nullptr;
  if (tid < 256) {
    const int bq = tid >> 6, kq = tid & 63;
    const float* xp = x + (size_t)(4 * bg + bq) * (TSTEPS * 2048) + n * 64 + kq;
    xbuf[1][bq * 96 + kq] = f2bf(xp[2048]);
    xr = xp[2 * 2048];
    xnext = xp + 3 * 2048;
  }
  float cg = c0[(size_t)b * 4096 + n * 128 + hl];

  // ---- acpre(0) = bias + Wih*x(0), x(0) fragged direct from global ----
  f32x4 acpre[2];
  {
    const float* q = x + (size_t)b * (TSTEPS * 2048) + n * 64 + 8 * quad;
    const f32x4 a0 = *(const f32x4*)q;
    const f32x4 a1 = *(const f32x4*)(q + 4);
    const f32x4 a2 = *(const f32x4*)(q + 32);
    const f32x4 a3 = *(const f32x4*)(q + 36);
    Frag xf0, xf1;
#pragma unroll
    for (int r = 0; r < 4; ++r) {
      xf0.s[r]     = f2bf(a0[r]);
      xf0.s[4 + r] = f2bf(a1[r]);
      xf1.s[r]     = f2bf(a2[r]);
      xf1.s[4 + r] = f2bf(a3[r]);
    }
#pragma unroll
    for (int T = 0; T < 2; ++T)
      acpre[T] = mf(wfr[1][T], xf1, mf(wfr[0][T], xf0, cb[T]));
  }
  __syncthreads();   // h(0), x(1) staged

  const int hoff  = b4 * 144 + quad * 8;     // h B-frag base
  const int xoff  = b4 * 96  + quad * 8;     // x B-frag base
  const int hwoff = b4 * 144 + hl;           // h write slot (writer lanes)
  float* outp = out + (size_t)b * (TSTEPS * 4096) + n * 128 + hl;
  float ho = 0.f;
  const f32x4 kzero = (f32x4){0.f, 0.f, 0.f, 0.f};

  // Step S (CUR=S&1): read h(S) from hbuf[CUR], x(S+1) frags from xbuf[NXT]
  // (written @S-1); stage x(S+2) into xbuf[CUR] (last read @S-1).  In-window:
  // 8 Whh MFMAs; tail: 4 Wih MFMAs -> acpre(S+1) (independent, interleaves).
  // Epilogue per lane on its tsel tile; ONE lgkm barrier at step end.
#define LSTM_STEP(CUR, NXT, S)                                               \
  {                                                                          \
    Frag hf0, hf1, hf2, hf3, xg0, xg1;                                       \
    hf0.s = *(const s16x8*)&hbuf[CUR][hoff];                                 \
    hf1.s = *(const s16x8*)&hbuf[CUR][hoff + 32];                            \
    hf2.s = *(const s16x8*)&hbuf[CUR][hoff + 64];                            \
    hf3.s = *(const s16x8*)&hbuf[CUR][hoff + 96];                            \
    xg0.s = *(const s16x8*)&xbuf[NXT][xoff];                                 \
    xg1.s = *(const s16x8*)&xbuf[NXT][xoff + 32];                            \
    if (tid < 256) {                                                         \
      xbuf[CUR][sxoff] = f2bf(xr);                                           \
      if ((S) + 3 < TSTEPS) { xr = *xnext; xnext += 2048; }                  \
    }                                                                        \
    f32x4 ac1[2], ac2[2];                                                    \
    _Pragma("unroll") for (int T = 0; T < 2; ++T) {                          \
      ac1[T] = mf(wfr[3][T], hf1, mf(wfr[2][T], hf0, acpre[T]));             \
      ac2[T] = mf(wfr[5][T], hf3, mf(wfr[4][T], hf2, kzero));                \
    }                                                                        \
    _Pragma("unroll") for (int T = 0; T < 2; ++T)                            \
      acpre[T] = mf(wfr[1][T], xg1, mf(wfr[0][T], xg0, cb[T]));              \
    const f32x4 ps = tsel ? (ac1[1] + ac2[1]) : (ac1[0] + ac2[0]);           \
    const float si = sig2(KSIG * ps[0]);                                     \
    const float sf = sig2(KSIG * ps[1]);                                     \
    const float sg = sig2(KTAN * ps[2]);                                     \
    const float so = sig2(KSIG * ps[3]);                                     \
    float cn = __builtin_fmaf(sf, cg, si);                                   \
    cn = __builtin_fmaf(-2.f, si * sg, cn);                                  \
    cg = cn;                                                                 \
    ho = so * __builtin_fmaf(-2.f, sig2(KTAN * cn), 1.f);                    \
    if (wr) {                                                                \
      hbuf[NXT][hwoff] = f2bf(ho);                                           \
      *outp = ho;                                                            \
    }                                                                        \
    outp += 4096;                                                            \
    sync_lds();                                                              \
  }

  for (int t = 0; t < TSTEPS; t += 2) {
    LSTM_STEP(0, 1, t);
    LSTM_STEP(1, 0, t + 1);
  }
#undef LSTM_STEP

  // ---- h_n / c_n (writer lanes) ----
  if (wr) {
    out[16777216 +         (size_t)b * 4096 + n * 128 + hl] = ho;
    out[16777216 + 65536 + (size_t)b * 4096 + n * 128 + hl] = cg;
  }
}

extern "C" void kernel_launch(void* const* d_in, const int* in_sizes, int n_in,
                              void* d_out, int out_size, void* d_ws, size_t ws_size,
                              hipStream_t stream) {
  const float* x   = (const float*)d_in[0];
  const float* h0  = (const float*)d_in[1];
  const float* c0  = (const float*)d_in[2];
  const float* wih = (const float*)d_in[3];
  const float* whh = (const float*)d_in[4];
  const float* bih = (const float*)d_in[5];
  const float* bhh = (const float*)d_in[6];
  float* out = (float*)d_out;
  wide_lstm<<<128, 1024, 0, stream>>>(x, h0, c0, wih, whh, bih, bhh, out);
}